// Round 5
// baseline (896.581 us; speedup 1.0000x reference)
//
#include <hip/hip_runtime.h>
#include <hip/hip_bf16.h>
#include <stdint.h>

typedef __hip_bfloat16 bf16;
typedef __attribute__((ext_vector_type(8))) short short8;
typedef __attribute__((ext_vector_type(4))) float floatx4;

#define DEV __device__ __forceinline__

DEV float bf2f(bf16 v) { return __bfloat162float(v); }
DEV bf16 f2b(float f) { return __float2bfloat16(f); }
DEV unsigned short f2bu(float f) {
  bf16 h = __float2bfloat16(f);
  union { bf16 h; unsigned short u; } c; c.h = h; return c.u;
}

// problem constants: B=32, N=4096, S=24, D=256, H=4, DH=64, ITERS=3

// ---- dtype detection: pos_ln_g is all-ones. u16[0]==0 -> f32 inputs, else bf16.
__global__ void detect_kernel(const unsigned short* probe, int* flag) {
  *flag = (probe[0] != 0) ? 1 : 0;
}

// ---- gather LN params + biases into canonical f32 block (3584 floats)
__global__ __launch_bounds__(256) void params_kernel(
    const void* s0, const void* s1, const void* s2, const void* s3, const void* s4,
    const void* s5, const void* s6, const void* s7, const void* s8, const void* s9,
    float* dst, const int* flagp)
{
  int idx = blockIdx.x * 256 + threadIdx.x;
  if (idx >= 3584) return;
  const void* srcs[10] = {s0, s1, s2, s3, s4, s5, s6, s7, s8, s9};
  int a, off;
  if (idx < 2048)      { a = idx >> 8; off = idx & 255; }
  else if (idx < 2816) { a = 8; off = idx - 2048; }
  else                 { a = 9; off = idx - 2816; }
  float v = (*flagp) ? bf2f(((const bf16*)srcs[a])[off]) : ((const float*)srcs[a])[off];
  dst[idx] = v;
}

// ---- weight transpose + convert to bf16: src[R][C] -> dst[C][R]
__global__ __launch_bounds__(256) void transpose_convert_kernel(
    const void* src, bf16* dst, int R, int C, const int* flagp)
{
  int idx = blockIdx.x * 256 + threadIdx.x;
  if (idx >= R * C) return;
  int r = idx / C, c = idx - r * C;
  bf16 v = (*flagp) ? ((const bf16*)src)[idx] : f2b(((const float*)src)[idx]);
  dst[(size_t)c * R + r] = v;
}

// ---------------- GEMM: C[M,N] = A[M,K](bf16) * Bt[N,K](bf16)^T (+bias f32)(+relu)
template<bool OUT_BF16, bool RELU, bool HAS_BIAS>
__global__ __launch_bounds__(256) void gemm_kernel(
    const bf16* __restrict__ A, const bf16* __restrict__ Bt,
    const float* __restrict__ bias, void* __restrict__ C,
    int M, int N, int K)
{
  __shared__ short As[128 * 72];
  __shared__ short Bs[128 * 72];
  const int tid = threadIdx.x;
  const int lane = tid & 63;
  const int wave = tid >> 6;
  const int wr = wave >> 1, wc = wave & 1;
  const int m16 = lane & 15, quad = lane >> 4;
  const long m0 = (long)blockIdx.y * 128, n0 = (long)blockIdx.x * 128;

  floatx4 acc[4][4];
#pragma unroll
  for (int i = 0; i < 4; i++)
#pragma unroll
    for (int j = 0; j < 4; j++) acc[i][j] = {0.f, 0.f, 0.f, 0.f};

  const int srow = tid >> 3;
  const int scol = (tid & 7) * 8;

  for (int kb = 0; kb < K; kb += 64) {
#pragma unroll
    for (int p = 0; p < 4; p++) {
      int row = srow + p * 32;
      uint4 av = *(const uint4*)(A + (m0 + row) * (long)K + kb + scol);
      *(uint4*)(&As[row * 72 + scol]) = av;
      uint4 bv = *(const uint4*)(Bt + (n0 + row) * (long)K + kb + scol);
      *(uint4*)(&Bs[row * 72 + scol]) = bv;
    }
    __syncthreads();
#pragma unroll
    for (int ks = 0; ks < 2; ks++) {
      short8 af[4], bfr[4];
#pragma unroll
      for (int t = 0; t < 4; t++) {
        af[t]  = *(const short8*)(&As[(wr * 64 + t * 16 + m16) * 72 + ks * 32 + quad * 8]);
        bfr[t] = *(const short8*)(&Bs[(wc * 64 + t * 16 + m16) * 72 + ks * 32 + quad * 8]);
      }
#pragma unroll
      for (int mt = 0; mt < 4; mt++)
#pragma unroll
        for (int nt = 0; nt < 4; nt++)
          acc[mt][nt] = __builtin_amdgcn_mfma_f32_16x16x32_bf16(af[mt], bfr[nt], acc[mt][nt], 0, 0, 0);
    }
    __syncthreads();
  }

#pragma unroll
  for (int mt = 0; mt < 4; mt++) {
#pragma unroll
    for (int nt = 0; nt < 4; nt++) {
      long col = n0 + wc * 64 + nt * 16 + m16;
      float bb = HAS_BIAS ? bias[col] : 0.f;
#pragma unroll
      for (int r = 0; r < 4; r++) {
        long row = m0 + wr * 64 + mt * 16 + quad * 4 + r;   // C/D: col=lane&15, row=quad*4+reg
        float v = acc[mt][nt][r] + bb;
        if (RELU) v = fmaxf(v, 0.f);
        if (OUT_BF16) ((bf16*)C)[row * N + col] = f2b(v);
        else          ((float*)C)[row * N + col] = v;
      }
    }
  }
}

// ---------------- LayerNorm over D=256, one wave per row
template<int MODE>  // 0: bf16 ws buf; 1: f32 ws buf; 2: external (flag-dtyped)
__global__ __launch_bounds__(256) void ln_kernel(
    const void* __restrict__ xin, const float* __restrict__ g, const float* __restrict__ bb,
    bf16* __restrict__ out, int rows, const int* flagp)
{
  int wave = threadIdx.x >> 6, lane = threadIdx.x & 63;
  long row = (long)blockIdx.x * 4 + wave;
  if (row >= rows) return;
  float v[4];
  bool f32in = (MODE == 1) || (MODE == 2 && *flagp == 0);
  if (f32in) {
    float4 f = *(const float4*)((const float*)xin + row * 256 + lane * 4);
    v[0] = f.x; v[1] = f.y; v[2] = f.z; v[3] = f.w;
  } else {
    uint2 u = *(const uint2*)((const bf16*)xin + row * 256 + lane * 4);
    v[0] = __uint_as_float((u.x & 0xffffu) << 16);
    v[1] = __uint_as_float(u.x & 0xffff0000u);
    v[2] = __uint_as_float((u.y & 0xffffu) << 16);
    v[3] = __uint_as_float(u.y & 0xffff0000u);
  }
  float s = v[0] + v[1] + v[2] + v[3];
  float sq = v[0] * v[0] + v[1] * v[1] + v[2] * v[2] + v[3] * v[3];
#pragma unroll
  for (int off = 32; off > 0; off >>= 1) {
    s  += __shfl_xor(s, off);
    sq += __shfl_xor(sq, off);
  }
  float m = s * (1.f / 256.f);
  float var = sq * (1.f / 256.f) - m * m;
  float rs = rsqrtf(var + 1e-5f);
  float4 gv = *(const float4*)(g + lane * 4);
  float4 bv = *(const float4*)(bb + lane * 4);
  union { unsigned short us[4]; uint2 u; } pk;
  pk.us[0] = f2bu((v[0] - m) * rs * gv.x + bv.x);
  pk.us[1] = f2bu((v[1] - m) * rs * gv.y + bv.y);
  pk.us[2] = f2bu((v[2] - m) * rs * gv.z + bv.z);
  pk.us[3] = f2bu((v[3] - m) * rs * gv.w + bv.w);
  *(uint2*)(out + row * 256 + lane * 4) = pk.u;
}

// ---------------- small utility kernels ----------------
__global__ __launch_bounds__(256) void init_slots_kernel(
    const void* __restrict__ cond, float* __restrict__ sF, bf16* __restrict__ sB,
    const int* flagp)
{
  int idx = blockIdx.x * 256 + threadIdx.x;  // 196608
  float v = (*flagp) ? bf2f(((const bf16*)cond)[idx]) : ((const float*)cond)[idx];
  sF[idx] = v;
  sB[idx] = f2b(v);
}

// q[768,256] f32 -> qp[b][h][32][64] bf16 (rows 24..31 zero, 0.125 scale folded in)
__global__ __launch_bounds__(256) void repack_q_kernel(
    const float* __restrict__ q, bf16* __restrict__ qp)
{
  int idx = blockIdx.x * 256 + threadIdx.x;  // 262144
  int dh = idx & 63, m = (idx >> 6) & 31, h = (idx >> 11) & 3, b = idx >> 13;
  float val = 0.f;
  if (m < 24) val = q[((size_t)(b * 24 + m)) * 256 + h * 64 + dh] * 0.125f;
  qp[idx] = f2b(val);
}

// ---- fused attention iteration v2: latency-optimized.
// grid (32 j-tiles of 128, 32 b), 4 waves = 4 heads. Softmax reductions in-register
// (shfl over quad) + tiny LDS cross-head combine. attn tile -> LDS bf16 (A-layout),
// PV partials + ws row-sums -> pupd[(b*4+h)*32+js][24*80] (col 64 = ws).
// LAST: writes attn mean-over-heads to out (+196608).
template<bool LAST>
__global__ __launch_bounds__(256) void attn_iter_kernel(
    const bf16* __restrict__ qp, const bf16* __restrict__ kbuf,
    const bf16* __restrict__ vT, float* __restrict__ pupd,
    void* __restrict__ out, const int* flagp)
{
  const int js = blockIdx.x;   // 0..31
  const int b  = blockIdx.y;   // 0..31
  const int h  = threadIdx.x >> 6;
  const int lane = threadIdx.x & 63;
  const int m16 = lane & 15, quad = lane >> 4;
  const int j0 = js * 128;

  __shared__ unsigned short att[4 * 24 * 136];   // bf16 A-layout, row stride 136
  __shared__ float red1[4 * 132];
  __shared__ float red2[4 * 132];

  // --- dots MFMA: C[slot][token] for this head ---
  short8 qf[2][2];
  const bf16* qpb = qp + (size_t)(b * 4 + h) * 2048;
#pragma unroll
  for (int mt = 0; mt < 2; mt++)
#pragma unroll
    for (int ks = 0; ks < 2; ks++)
      qf[mt][ks] = *(const short8*)(qpb + (mt * 16 + m16) * 64 + ks * 32 + quad * 8);

  floatx4 dacc[2][8];
#pragma unroll
  for (int i = 0; i < 2; i++)
#pragma unroll
    for (int j = 0; j < 8; j++) dacc[i][j] = {0.f, 0.f, 0.f, 0.f};

  const bf16* kb = kbuf + ((size_t)b * 4096 + j0) * 256 + h * 64;
#pragma unroll
  for (int ks = 0; ks < 2; ks++)
#pragma unroll
    for (int nt = 0; nt < 8; nt++) {
      short8 bfr = *(const short8*)(kb + (size_t)(nt * 16 + m16) * 256 + ks * 32 + quad * 8);
      dacc[0][nt] = __builtin_amdgcn_mfma_f32_16x16x32_bf16(qf[0][ks], bfr, dacc[0][nt], 0, 0, 0);
      dacc[1][nt] = __builtin_amdgcn_mfma_f32_16x16x32_bf16(qf[1][ks], bfr, dacc[1][nt], 0, 0, 0);
    }

  // rows: mt*16 + quad*4 + r; valid (<24) iff mt==0 || quad<2
  const bool mt1_valid = (quad < 2);

  // --- per-column max: in-lane over rows, shfl over quad, LDS over heads ---
  float cmax[8];
#pragma unroll
  for (int nt = 0; nt < 8; nt++) {
    float m = fmaxf(fmaxf(dacc[0][nt][0], dacc[0][nt][1]), fmaxf(dacc[0][nt][2], dacc[0][nt][3]));
    if (mt1_valid)
      m = fmaxf(m, fmaxf(fmaxf(dacc[1][nt][0], dacc[1][nt][1]), fmaxf(dacc[1][nt][2], dacc[1][nt][3])));
    m = fmaxf(m, __shfl_xor(m, 16));
    m = fmaxf(m, __shfl_xor(m, 32));
    cmax[nt] = m;
  }
  if (quad == 0) {
#pragma unroll
    for (int nt = 0; nt < 8; nt++) red1[h * 132 + nt * 16 + m16] = cmax[nt];
  }
  __syncthreads();

  // --- exp + per-column sums ---
  float csum[8];
#pragma unroll
  for (int nt = 0; nt < 8; nt++) {
    int c = nt * 16 + m16;
    float g = fmaxf(fmaxf(red1[c], red1[132 + c]), fmaxf(red1[264 + c], red1[396 + c]));
    float s = 0.f;
#pragma unroll
    for (int r = 0; r < 4; r++) {
      float e = __expf(dacc[0][nt][r] - g);
      dacc[0][nt][r] = e; s += e;
    }
#pragma unroll
    for (int r = 0; r < 4; r++) {
      float e = mt1_valid ? __expf(dacc[1][nt][r] - g) : 0.f;
      dacc[1][nt][r] = e; s += e;
    }
    s += __shfl_xor(s, 16);
    s += __shfl_xor(s, 32);
    csum[nt] = s;
  }
  if (quad == 0) {
#pragma unroll
    for (int nt = 0; nt < 8; nt++) red2[h * 132 + nt * 16 + m16] = csum[nt];
  }
  __syncthreads();

  // --- normalize + eps, write att bf16 (A-layout), ws row partials ---
  float wsum[2][4] = {{0.f, 0.f, 0.f, 0.f}, {0.f, 0.f, 0.f, 0.f}};
#pragma unroll
  for (int nt = 0; nt < 8; nt++) {
    int c = nt * 16 + m16;
    float inv = 1.f / (red2[c] + red2[132 + c] + red2[264 + c] + red2[396 + c]);
#pragma unroll
    for (int r = 0; r < 4; r++) {
      float a = dacc[0][nt][r] * inv + 1e-8f;
      int row = quad * 4 + r;
      att[h * 3264 + row * 136 + c] = f2bu(a);
      wsum[0][r] += a;
    }
    if (mt1_valid) {
#pragma unroll
      for (int r = 0; r < 4; r++) {
        float a = dacc[1][nt][r] * inv + 1e-8f;
        int row = 16 + quad * 4 + r;
        att[h * 3264 + row * 136 + c] = f2bu(a);
        wsum[1][r] += a;
      }
    }
  }
  // sum ws over the 16 m16-lanes (cols) -> per-row totals over 128 tokens
#pragma unroll
  for (int mt = 0; mt < 2; mt++)
#pragma unroll
    for (int r = 0; r < 4; r++) {
      float w = wsum[mt][r];
      w += __shfl_xor(w, 1); w += __shfl_xor(w, 2);
      w += __shfl_xor(w, 4); w += __shfl_xor(w, 8);
      wsum[mt][r] = w;
    }
  float* dst = pupd + ((size_t)(b * 4 + h) * 32 + js) * 1920;
  if (m16 == 0) {
#pragma unroll
    for (int mt = 0; mt < 2; mt++)
#pragma unroll
      for (int r = 0; r < 4; r++) {
        int row = mt * 16 + quad * 4 + r;
        if (row < 24) dst[row * 80 + 64] = wsum[mt][r];
      }
  }
  __syncthreads();

  // --- PV: upd[slot][d64] partial over this j-tile ---
  floatx4 uacc[2][4];
#pragma unroll
  for (int i = 0; i < 2; i++)
#pragma unroll
    for (int j = 0; j < 4; j++) uacc[i][j] = {0.f, 0.f, 0.f, 0.f};
  int arow1 = 16 + m16; if (arow1 > 23) arow1 = 23;   // clamped garbage rows -> C rows >=24, unused
  const bf16* vb0 = vT + (size_t)b * 4096 + j0;
#pragma unroll
  for (int ks = 0; ks < 4; ks++) {
    short8 a0 = *(const short8*)(&att[h * 3264 + m16 * 136 + ks * 32 + quad * 8]);
    short8 a1 = *(const short8*)(&att[h * 3264 + arow1 * 136 + ks * 32 + quad * 8]);
#pragma unroll
    for (int nt = 0; nt < 4; nt++) {
      short8 bfr = *(const short8*)(vb0 + (size_t)(h * 64 + nt * 16 + m16) * 131072 + ks * 32 + quad * 8);
      uacc[0][nt] = __builtin_amdgcn_mfma_f32_16x16x32_bf16(a0, bfr, uacc[0][nt], 0, 0, 0);
      uacc[1][nt] = __builtin_amdgcn_mfma_f32_16x16x32_bf16(a1, bfr, uacc[1][nt], 0, 0, 0);
    }
  }
#pragma unroll
  for (int mt = 0; mt < 2; mt++)
#pragma unroll
    for (int nt = 0; nt < 4; nt++)
#pragma unroll
      for (int r = 0; r < 4; r++) {
        int row = mt * 16 + quad * 4 + r;
        if (row < 24) dst[row * 80 + nt * 16 + m16] = uacc[mt][nt][r];
      }

  if (LAST) {
    // attn mean over heads: 24 slots x 128 tokens from att LDS
    int c = threadIdx.x & 127;
    int half = threadIdx.x >> 7;
#pragma unroll
    for (int i0 = 0; i0 < 12; i0++) {
      int i = half * 12 + i0;
      float s = bf2f(__ushort_as_bfloat16(att[i * 136 + c]))
              + bf2f(__ushort_as_bfloat16(att[3264 + i * 136 + c]))
              + bf2f(__ushort_as_bfloat16(att[6528 + i * 136 + c]))
              + bf2f(__ushort_as_bfloat16(att[9792 + i * 136 + c]));
      size_t oidx = ((size_t)(b * 24 + i)) * 4096 + j0 + c;
      if (*flagp) ((bf16*)out)[196608 + oidx] = f2b(0.25f * s);
      else        ((float*)out)[196608 + oidx] = 0.25f * s;
    }
  }
}

// reduce 32 partials, divide by ws, pack to bf16 updB[b*24+i][h*64+d]
__global__ __launch_bounds__(256) void upd_final_kernel(
    const float* __restrict__ pupd, bf16* __restrict__ updB)
{
  int bh = blockIdx.x; int b = bh >> 2, h = bh & 3;
  int t = threadIdx.x;
  const float* base = pupd + (size_t)bh * 32 * 1920;
#pragma unroll
  for (int rr = 0; rr < 6; rr++) {
    int idx = rr * 256 + t;          // 0..1535
    int i = idx >> 6, d = idx & 63;
    float v = 0.f, w = 0.f;
    for (int p = 0; p < 32; p++) {
      v += base[p * 1920 + i * 80 + d];
      w += base[p * 1920 + i * 80 + 64];
    }
    updB[((size_t)(b * 24 + i)) * 256 + h * 64 + d] = f2b(v / w);
  }
}

__global__ __launch_bounds__(256) void gru_gate_kernel(
    const float* __restrict__ gi, const float* __restrict__ gh,
    float* __restrict__ sF, bf16* __restrict__ sB)
{
  int row = blockIdx.x, d = threadIdx.x;
  size_t o = (size_t)row * 768;
  float ir = gi[o + d], iz = gi[o + 256 + d], inn = gi[o + 512 + d];
  float hr = gh[o + d], hz = gh[o + 256 + d], hn = gh[o + 512 + d];
  float hv = sF[(size_t)row * 256 + d];
  float r = 1.f / (1.f + __expf(-(ir + hr)));
  float z = 1.f / (1.f + __expf(-(iz + hz)));
  float nn = tanhf(inn + r * hn);
  float sv = (1.f - z) * nn + z * hv;
  sF[(size_t)row * 256 + d] = sv;
  sB[(size_t)row * 256 + d] = f2b(sv);
}

__global__ __launch_bounds__(256) void out_slots_kernel(
    const float* __restrict__ sF, void* __restrict__ out, const int* flagp)
{
  int idx = blockIdx.x * 256 + threadIdx.x;  // 196608
  float v = sF[idx];
  if (*flagp) ((bf16*)out)[idx] = f2b(v);
  else        ((float*)out)[idx] = v;
}

// ---------------- workspace layout ----------------
static constexpr size_t SZ_BIG   = (size_t)32 * 4096 * 256 * 2;       // 67108864
static constexpr size_t OFF_BUF1 = 0;
static constexpr size_t OFF_BUF2 = OFF_BUF1 + SZ_BIG;
static constexpr size_t OFF_K    = OFF_BUF2 + SZ_BIG;
static constexpr size_t OFF_V    = OFF_K + SZ_BIG;                    // vT bf16 [256][131072]
static constexpr size_t OFF_Q    = OFF_V + SZ_BIG;                    // f32 [768][256]
static constexpr size_t OFF_QP   = OFF_Q + (size_t)768 * 256 * 4;
static constexpr size_t OFF_SNB  = OFF_QP + (size_t)32 * 4 * 32 * 64 * 2;
static constexpr size_t OFF_SF   = OFF_SNB + (size_t)768 * 256 * 2;
static constexpr size_t OFF_SB   = OFF_SF + (size_t)768 * 256 * 4;
static constexpr size_t OFF_UPD  = OFF_SB + (size_t)768 * 256 * 2;
static constexpr size_t OFF_GI   = OFF_UPD + (size_t)768 * 256 * 2;
static constexpr size_t OFF_GH   = OFF_GI + (size_t)768 * 768 * 4;
static constexpr size_t OFF_PUPD = OFF_GH + (size_t)768 * 768 * 4;    // 128*32*1920*4 = 31.5 MB
static constexpr size_t OFF_W1T  = OFF_PUPD + (size_t)128 * 32 * 1920 * 4;
static constexpr size_t OFF_W2T  = OFF_W1T + (size_t)256 * 256 * 2;
static constexpr size_t OFF_WQT  = OFF_W2T + (size_t)256 * 256 * 2;
static constexpr size_t OFF_WKT  = OFF_WQT + (size_t)256 * 256 * 2;
static constexpr size_t OFF_WVT  = OFF_WKT + (size_t)256 * 256 * 2;
static constexpr size_t OFF_GWIT = OFF_WVT + (size_t)256 * 256 * 2;
static constexpr size_t OFF_GWHT = OFF_GWIT + (size_t)256 * 768 * 2;
static constexpr size_t OFF_PAR  = OFF_GWHT + (size_t)256 * 768 * 2;  // 3584 f32
static constexpr size_t OFF_FLAG = OFF_PAR + (size_t)3584 * 4;
static constexpr size_t WS_NEED  = OFF_FLAG + 256;

extern "C" void kernel_launch(void* const* d_in, const int* in_sizes, int n_in,
                              void* d_out, int out_size, void* d_ws, size_t ws_size,
                              hipStream_t stream) {
  (void)in_sizes; (void)n_in; (void)out_size;
  if (ws_size < WS_NEED) return;

  const void* x         = d_in[0];
  const void* cond      = d_in[1];
  const void* pos_ln_g  = d_in[2];
  const void* pos_ln_b  = d_in[3];
  const void* pos_w1    = d_in[4];
  const void* pos_b1    = d_in[5];
  const void* pos_w2    = d_in[6];
  const void* pos_b2    = d_in[7];
  const void* in_ln_g   = d_in[8];
  const void* in_ln_b   = d_in[9];
  const void* slot_ln_g = d_in[10];
  const void* slot_ln_b = d_in[11];
  const void* Wq        = d_in[12];
  const void* Wk        = d_in[13];
  const void* Wv        = d_in[14];
  const void* gru_wi    = d_in[15];
  const void* gru_wh    = d_in[16];
  const void* gru_bi    = d_in[17];
  const void* gru_bh    = d_in[18];

  char* ws = (char*)d_ws;
  bf16*  buf1  = (bf16*)(ws + OFF_BUF1);
  bf16*  buf2  = (bf16*)(ws + OFF_BUF2);
  bf16*  kbuf  = (bf16*)(ws + OFF_K);
  bf16*  vT    = (bf16*)(ws + OFF_V);
  float* qbuf  = (float*)(ws + OFF_Q);
  bf16*  qp    = (bf16*)(ws + OFF_QP);
  bf16*  snb   = (bf16*)(ws + OFF_SNB);
  float* sF    = (float*)(ws + OFF_SF);
  bf16*  sB    = (bf16*)(ws + OFF_SB);
  bf16*  updB  = (bf16*)(ws + OFF_UPD);
  float* gi    = (float*)(ws + OFF_GI);
  float* gh    = (float*)(ws + OFF_GH);
  float* pupd  = (float*)(ws + OFF_PUPD);
  bf16*  w1t   = (bf16*)(ws + OFF_W1T);
  bf16*  w2t   = (bf16*)(ws + OFF_W2T);
  bf16*  wqt   = (bf16*)(ws + OFF_WQT);
  bf16*  wkt   = (bf16*)(ws + OFF_WKT);
  bf16*  wvt   = (bf16*)(ws + OFF_WVT);
  bf16*  gwit  = (bf16*)(ws + OFF_GWIT);
  bf16*  gwht  = (bf16*)(ws + OFF_GWHT);
  float* par   = (float*)(ws + OFF_PAR);
  int*   flagp = (int*)(ws + OFF_FLAG);

  // --- dtype detection + canonicalization ---
  detect_kernel<<<1, 1, 0, stream>>>((const unsigned short*)pos_ln_g, flagp);
  params_kernel<<<14, 256, 0, stream>>>(pos_ln_g, pos_ln_b, pos_b1, pos_b2,
                                        in_ln_g, in_ln_b, slot_ln_g, slot_ln_b,
                                        gru_bi, gru_bh, par, flagp);
  transpose_convert_kernel<<<256, 256, 0, stream>>>(pos_w1, w1t, 256, 256, flagp);
  transpose_convert_kernel<<<256, 256, 0, stream>>>(pos_w2, w2t, 256, 256, flagp);
  transpose_convert_kernel<<<256, 256, 0, stream>>>(Wq, wqt, 256, 256, flagp);
  transpose_convert_kernel<<<256, 256, 0, stream>>>(Wk, wkt, 256, 256, flagp);
  transpose_convert_kernel<<<256, 256, 0, stream>>>(Wv, wvt, 256, 256, flagp);
  transpose_convert_kernel<<<768, 256, 0, stream>>>(gru_wi, gwit, 256, 768, flagp);
  transpose_convert_kernel<<<768, 256, 0, stream>>>(gru_wh, gwht, 256, 768, flagp);
  init_slots_kernel<<<768, 256, 0, stream>>>(cond, sF, sB, flagp);

  // --- phase A: positional MLP + input LN + K/V projections ---
  ln_kernel<2><<<32768, 256, 0, stream>>>(x, par + 0, par + 256, buf1, 131072, flagp);
  gemm_kernel<true, true, true><<<dim3(2, 1024), 256, 0, stream>>>(
      buf1, w1t, par + 512, buf2, 131072, 256, 256);                   // h1 = relu(xln@w1+b1)
  gemm_kernel<true, false, true><<<dim3(2, 1024), 256, 0, stream>>>(
      buf2, w2t, par + 768, buf1, 131072, 256, 256);                   // feats = h1@w2+b2
  ln_kernel<0><<<32768, 256, 0, stream>>>(buf1, par + 1024, par + 1280, buf2, 131072, flagp);
  gemm_kernel<true, false, false><<<dim3(2, 1024), 256, 0, stream>>>(
      buf2, wkt, nullptr, kbuf, 131072, 256, 256);                     // k [token][d]
  gemm_kernel<true, false, false><<<dim3(1024, 2), 256, 0, stream>>>(
      wvt, buf2, nullptr, vT, 256, 131072, 256);                       // vT [d][token]

  // --- phase B: 3 slot-attention iterations ---
  for (int it = 0; it < 3; it++) {
    ln_kernel<1><<<192, 256, 0, stream>>>(sF, par + 1536, par + 1792, snb, 768, flagp);
    gemm_kernel<false, false, false><<<dim3(2, 6), 256, 0, stream>>>(
        snb, wqt, nullptr, qbuf, 768, 256, 256);                       // q (f32)
    repack_q_kernel<<<1024, 256, 0, stream>>>(qbuf, qp);
    if (it == 2)
      attn_iter_kernel<true><<<dim3(32, 32), 256, 0, stream>>>(qp, kbuf, vT, pupd, d_out, flagp);
    else
      attn_iter_kernel<false><<<dim3(32, 32), 256, 0, stream>>>(qp, kbuf, vT, pupd, d_out, flagp);
    upd_final_kernel<<<128, 256, 0, stream>>>(pupd, updB);
    gemm_kernel<false, false, true><<<dim3(6, 6), 256, 0, stream>>>(
        updB, gwit, par + 2048, gi, 768, 768, 256);                    // gi
    gemm_kernel<false, false, true><<<dim3(6, 6), 256, 0, stream>>>(
        sB, gwht, par + 2816, gh, 768, 768, 256);                      // gh
    gru_gate_kernel<<<768, 256, 0, stream>>>(gi, gh, sF, sB);
  }

  // --- outputs ---
  out_slots_kernel<<<768, 256, 0, stream>>>(sF, d_out, flagp);
}

// Round 6
// 669.720 us; speedup vs baseline: 1.3387x; 1.3387x over previous
//
#include <hip/hip_runtime.h>
#include <hip/hip_bf16.h>
#include <stdint.h>

typedef __hip_bfloat16 bf16;
typedef __attribute__((ext_vector_type(8))) short short8;
typedef __attribute__((ext_vector_type(4))) float floatx4;

#define DEV __device__ __forceinline__

DEV float bf2f(bf16 v) { return __bfloat162float(v); }
DEV bf16 f2b(float f) { return __float2bfloat16(f); }
DEV unsigned short f2bu(float f) {
  bf16 h = __float2bfloat16(f);
  union { bf16 h; unsigned short u; } c; c.h = h; return c.u;
}

// problem constants: B=32, N=4096, S=24, D=256, H=4, DH=64, ITERS=3

// ---- dtype detection: pos_ln_g is all-ones. u16[0]==0 -> f32 inputs, else bf16.
__global__ void detect_kernel(const unsigned short* probe, int* flag) {
  *flag = (probe[0] != 0) ? 1 : 0;
}

// ---- gather LN params + biases into canonical f32 block (3584 floats)
__global__ __launch_bounds__(256) void params_kernel(
    const void* s0, const void* s1, const void* s2, const void* s3, const void* s4,
    const void* s5, const void* s6, const void* s7, const void* s8, const void* s9,
    float* dst, const int* flagp)
{
  int idx = blockIdx.x * 256 + threadIdx.x;
  if (idx >= 3584) return;
  const void* srcs[10] = {s0, s1, s2, s3, s4, s5, s6, s7, s8, s9};
  int a, off;
  if (idx < 2048)      { a = idx >> 8; off = idx & 255; }
  else if (idx < 2816) { a = 8; off = idx - 2048; }
  else                 { a = 9; off = idx - 2816; }
  float v = (*flagp) ? bf2f(((const bf16*)srcs[a])[off]) : ((const float*)srcs[a])[off];
  dst[idx] = v;
}

// ---- weight transpose + convert to bf16: src[R][C] -> dst[C][R]
__global__ __launch_bounds__(256) void transpose_convert_kernel(
    const void* src, bf16* dst, int R, int C, const int* flagp)
{
  int idx = blockIdx.x * 256 + threadIdx.x;
  if (idx >= R * C) return;
  int r = idx / C, c = idx - r * C;
  bf16 v = (*flagp) ? ((const bf16*)src)[idx] : f2b(((const float*)src)[idx]);
  dst[(size_t)c * R + r] = v;
}

// ---------------- GEMM: C[M,N] = A[M,K](bf16) * Bt[N,K](bf16)^T (+bias f32)(+relu)
template<bool OUT_BF16, bool RELU, bool HAS_BIAS>
__global__ __launch_bounds__(256) void gemm_kernel(
    const bf16* __restrict__ A, const bf16* __restrict__ Bt,
    const float* __restrict__ bias, void* __restrict__ C,
    int M, int N, int K)
{
  __shared__ short As[128 * 72];
  __shared__ short Bs[128 * 72];
  const int tid = threadIdx.x;
  const int lane = tid & 63;
  const int wave = tid >> 6;
  const int wr = wave >> 1, wc = wave & 1;
  const int m16 = lane & 15, quad = lane >> 4;
  const long m0 = (long)blockIdx.y * 128, n0 = (long)blockIdx.x * 128;

  floatx4 acc[4][4];
#pragma unroll
  for (int i = 0; i < 4; i++)
#pragma unroll
    for (int j = 0; j < 4; j++) acc[i][j] = {0.f, 0.f, 0.f, 0.f};

  const int srow = tid >> 3;
  const int scol = (tid & 7) * 8;

  for (int kb = 0; kb < K; kb += 64) {
#pragma unroll
    for (int p = 0; p < 4; p++) {
      int row = srow + p * 32;
      uint4 av = *(const uint4*)(A + (m0 + row) * (long)K + kb + scol);
      *(uint4*)(&As[row * 72 + scol]) = av;
      uint4 bv = *(const uint4*)(Bt + (n0 + row) * (long)K + kb + scol);
      *(uint4*)(&Bs[row * 72 + scol]) = bv;
    }
    __syncthreads();
#pragma unroll
    for (int ks = 0; ks < 2; ks++) {
      short8 af[4], bfr[4];
#pragma unroll
      for (int t = 0; t < 4; t++) {
        af[t]  = *(const short8*)(&As[(wr * 64 + t * 16 + m16) * 72 + ks * 32 + quad * 8]);
        bfr[t] = *(const short8*)(&Bs[(wc * 64 + t * 16 + m16) * 72 + ks * 32 + quad * 8]);
      }
#pragma unroll
      for (int mt = 0; mt < 4; mt++)
#pragma unroll
        for (int nt = 0; nt < 4; nt++)
          acc[mt][nt] = __builtin_amdgcn_mfma_f32_16x16x32_bf16(af[mt], bfr[nt], acc[mt][nt], 0, 0, 0);
    }
    __syncthreads();
  }

#pragma unroll
  for (int mt = 0; mt < 4; mt++) {
#pragma unroll
    for (int nt = 0; nt < 4; nt++) {
      long col = n0 + wc * 64 + nt * 16 + m16;
      float bb = HAS_BIAS ? bias[col] : 0.f;
#pragma unroll
      for (int r = 0; r < 4; r++) {
        long row = m0 + wr * 64 + mt * 16 + quad * 4 + r;   // C/D: col=lane&15, row=quad*4+reg
        float v = acc[mt][nt][r] + bb;
        if (RELU) v = fmaxf(v, 0.f);
        if (OUT_BF16) ((bf16*)C)[row * N + col] = f2b(v);
        else          ((float*)C)[row * N + col] = v;
      }
    }
  }
}

// ---------------- LayerNorm over D=256, one wave per row
template<int MODE>  // 0: bf16 ws buf; 1: f32 ws buf; 2: external (flag-dtyped)
__global__ __launch_bounds__(256) void ln_kernel(
    const void* __restrict__ xin, const float* __restrict__ g, const float* __restrict__ bb,
    bf16* __restrict__ out, int rows, const int* flagp)
{
  int wave = threadIdx.x >> 6, lane = threadIdx.x & 63;
  long row = (long)blockIdx.x * 4 + wave;
  if (row >= rows) return;
  float v[4];
  bool f32in = (MODE == 1) || (MODE == 2 && *flagp == 0);
  if (f32in) {
    float4 f = *(const float4*)((const float*)xin + row * 256 + lane * 4);
    v[0] = f.x; v[1] = f.y; v[2] = f.z; v[3] = f.w;
  } else {
    uint2 u = *(const uint2*)((const bf16*)xin + row * 256 + lane * 4);
    v[0] = __uint_as_float((u.x & 0xffffu) << 16);
    v[1] = __uint_as_float(u.x & 0xffff0000u);
    v[2] = __uint_as_float((u.y & 0xffffu) << 16);
    v[3] = __uint_as_float(u.y & 0xffff0000u);
  }
  float s = v[0] + v[1] + v[2] + v[3];
  float sq = v[0] * v[0] + v[1] * v[1] + v[2] * v[2] + v[3] * v[3];
#pragma unroll
  for (int off = 32; off > 0; off >>= 1) {
    s  += __shfl_xor(s, off);
    sq += __shfl_xor(sq, off);
  }
  float m = s * (1.f / 256.f);
  float var = sq * (1.f / 256.f) - m * m;
  float rs = rsqrtf(var + 1e-5f);
  float4 gv = *(const float4*)(g + lane * 4);
  float4 bv = *(const float4*)(bb + lane * 4);
  union { unsigned short us[4]; uint2 u; } pk;
  pk.us[0] = f2bu((v[0] - m) * rs * gv.x + bv.x);
  pk.us[1] = f2bu((v[1] - m) * rs * gv.y + bv.y);
  pk.us[2] = f2bu((v[2] - m) * rs * gv.z + bv.z);
  pk.us[3] = f2bu((v[3] - m) * rs * gv.w + bv.w);
  *(uint2*)(out + row * 256 + lane * 4) = pk.u;
}

// ---------------- small utility kernels ----------------
__global__ __launch_bounds__(256) void init_slots_kernel(
    const void* __restrict__ cond, float* __restrict__ sF, bf16* __restrict__ sB,
    const int* flagp)
{
  int idx = blockIdx.x * 256 + threadIdx.x;  // 196608
  float v = (*flagp) ? bf2f(((const bf16*)cond)[idx]) : ((const float*)cond)[idx];
  sF[idx] = v;
  sB[idx] = f2b(v);
}

// q[768,256] f32 -> qp[b][h][32][64] bf16 (rows 24..31 zero, 0.125 scale folded in)
__global__ __launch_bounds__(256) void repack_q_kernel(
    const float* __restrict__ q, bf16* __restrict__ qp)
{
  int idx = blockIdx.x * 256 + threadIdx.x;  // 262144
  int dh = idx & 63, m = (idx >> 6) & 31, h = (idx >> 11) & 3, b = idx >> 13;
  float val = 0.f;
  if (m < 24) val = q[((size_t)(b * 24 + m)) * 256 + h * 64 + dh] * 0.125f;
  qp[idx] = f2b(val);
}

// ---- fused attention iteration: dots -> softmax(96 per token) -> (attn+eps)@V partials
// grid (32 j-tiles of 128, 32 b), 4 waves = 4 heads. Softmax reductions in-register
// (shfl over quad) + tiny LDS cross-head combine. attn tile -> LDS bf16 (A-layout),
// PV partials + ws row-sums -> pupd[(b*4+h)*32+js][24*80] (col 64 = ws).
// LAST: writes attn mean-over-heads to out (+196608).
template<bool LAST>
__global__ __launch_bounds__(256) void attn_iter_kernel(
    const bf16* __restrict__ qp, const bf16* __restrict__ kbuf,
    const bf16* __restrict__ vT, float* __restrict__ pupd,
    void* __restrict__ out, const int* flagp)
{
  const int js = blockIdx.x;   // 0..31
  const int b  = blockIdx.y;   // 0..31
  const int h  = threadIdx.x >> 6;
  const int lane = threadIdx.x & 63;
  const int m16 = lane & 15, quad = lane >> 4;
  const int j0 = js * 128;

  __shared__ unsigned short att[4 * 24 * 136];   // bf16 A-layout, row stride 136
  __shared__ float red1[4 * 132];
  __shared__ float red2[4 * 132];

  // --- dots MFMA: C[slot][token] for this head ---
  short8 qf[2][2];
  const bf16* qpb = qp + (size_t)(b * 4 + h) * 2048;
#pragma unroll
  for (int mt = 0; mt < 2; mt++)
#pragma unroll
    for (int ks = 0; ks < 2; ks++)
      qf[mt][ks] = *(const short8*)(qpb + (mt * 16 + m16) * 64 + ks * 32 + quad * 8);

  floatx4 dacc[2][8];
#pragma unroll
  for (int i = 0; i < 2; i++)
#pragma unroll
    for (int j = 0; j < 8; j++) dacc[i][j] = {0.f, 0.f, 0.f, 0.f};

  const bf16* kb = kbuf + ((size_t)b * 4096 + j0) * 256 + h * 64;
#pragma unroll
  for (int ks = 0; ks < 2; ks++)
#pragma unroll
    for (int nt = 0; nt < 8; nt++) {
      short8 bfr = *(const short8*)(kb + (size_t)(nt * 16 + m16) * 256 + ks * 32 + quad * 8);
      dacc[0][nt] = __builtin_amdgcn_mfma_f32_16x16x32_bf16(qf[0][ks], bfr, dacc[0][nt], 0, 0, 0);
      dacc[1][nt] = __builtin_amdgcn_mfma_f32_16x16x32_bf16(qf[1][ks], bfr, dacc[1][nt], 0, 0, 0);
    }

  // rows: mt*16 + quad*4 + r; valid (<24) iff mt==0 || quad<2
  const bool mt1_valid = (quad < 2);

  // --- per-column max: in-lane over rows, shfl over quad, LDS over heads ---
  float cmax[8];
#pragma unroll
  for (int nt = 0; nt < 8; nt++) {
    float m = fmaxf(fmaxf(dacc[0][nt][0], dacc[0][nt][1]), fmaxf(dacc[0][nt][2], dacc[0][nt][3]));
    if (mt1_valid)
      m = fmaxf(m, fmaxf(fmaxf(dacc[1][nt][0], dacc[1][nt][1]), fmaxf(dacc[1][nt][2], dacc[1][nt][3])));
    m = fmaxf(m, __shfl_xor(m, 16));
    m = fmaxf(m, __shfl_xor(m, 32));
    cmax[nt] = m;
  }
  if (quad == 0) {
#pragma unroll
    for (int nt = 0; nt < 8; nt++) red1[h * 132 + nt * 16 + m16] = cmax[nt];
  }
  __syncthreads();

  // --- exp + per-column sums ---
  float csum[8];
#pragma unroll
  for (int nt = 0; nt < 8; nt++) {
    int c = nt * 16 + m16;
    float g = fmaxf(fmaxf(red1[c], red1[132 + c]), fmaxf(red1[264 + c], red1[396 + c]));
    float s = 0.f;
#pragma unroll
    for (int r = 0; r < 4; r++) {
      float e = __expf(dacc[0][nt][r] - g);
      dacc[0][nt][r] = e; s += e;
    }
#pragma unroll
    for (int r = 0; r < 4; r++) {
      float e = mt1_valid ? __expf(dacc[1][nt][r] - g) : 0.f;
      dacc[1][nt][r] = e; s += e;
    }
    s += __shfl_xor(s, 16);
    s += __shfl_xor(s, 32);
    csum[nt] = s;
  }
  if (quad == 0) {
#pragma unroll
    for (int nt = 0; nt < 8; nt++) red2[h * 132 + nt * 16 + m16] = csum[nt];
  }
  __syncthreads();

  // --- normalize + eps, write att bf16 (A-layout), ws row partials ---
  float wsum[2][4] = {{0.f, 0.f, 0.f, 0.f}, {0.f, 0.f, 0.f, 0.f}};
#pragma unroll
  for (int nt = 0; nt < 8; nt++) {
    int c = nt * 16 + m16;
    float inv = 1.f / (red2[c] + red2[132 + c] + red2[264 + c] + red2[396 + c]);
#pragma unroll
    for (int r = 0; r < 4; r++) {
      float a = dacc[0][nt][r] * inv + 1e-8f;
      int row = quad * 4 + r;
      att[h * 3264 + row * 136 + c] = f2bu(a);
      wsum[0][r] += a;
    }
    if (mt1_valid) {
#pragma unroll
      for (int r = 0; r < 4; r++) {
        float a = dacc[1][nt][r] * inv + 1e-8f;
        int row = 16 + quad * 4 + r;
        att[h * 3264 + row * 136 + c] = f2bu(a);
        wsum[1][r] += a;
      }
    }
  }
  // sum ws over the 16 m16-lanes (cols) -> per-row totals over 128 tokens
#pragma unroll
  for (int mt = 0; mt < 2; mt++)
#pragma unroll
    for (int r = 0; r < 4; r++) {
      float w = wsum[mt][r];
      w += __shfl_xor(w, 1); w += __shfl_xor(w, 2);
      w += __shfl_xor(w, 4); w += __shfl_xor(w, 8);
      wsum[mt][r] = w;
    }
  float* dst = pupd + ((size_t)(b * 4 + h) * 32 + js) * 1920;
  if (m16 == 0) {
#pragma unroll
    for (int mt = 0; mt < 2; mt++)
#pragma unroll
      for (int r = 0; r < 4; r++) {
        int row = mt * 16 + quad * 4 + r;
        if (row < 24) dst[row * 80 + 64] = wsum[mt][r];
      }
  }
  __syncthreads();

  // --- PV: upd[slot][d64] partial over this j-tile ---
  floatx4 uacc[2][4];
#pragma unroll
  for (int i = 0; i < 2; i++)
#pragma unroll
    for (int j = 0; j < 4; j++) uacc[i][j] = {0.f, 0.f, 0.f, 0.f};
  int arow1 = 16 + m16; if (arow1 > 23) arow1 = 23;   // clamped garbage rows -> C rows >=24, unused
  const bf16* vb0 = vT + (size_t)b * 4096 + j0;
#pragma unroll
  for (int ks = 0; ks < 4; ks++) {
    short8 a0 = *(const short8*)(&att[h * 3264 + m16 * 136 + ks * 32 + quad * 8]);
    short8 a1 = *(const short8*)(&att[h * 3264 + arow1 * 136 + ks * 32 + quad * 8]);
#pragma unroll
    for (int nt = 0; nt < 4; nt++) {
      short8 bfr = *(const short8*)(vb0 + (size_t)(h * 64 + nt * 16 + m16) * 131072 + ks * 32 + quad * 8);
      uacc[0][nt] = __builtin_amdgcn_mfma_f32_16x16x32_bf16(a0, bfr, uacc[0][nt], 0, 0, 0);
      uacc[1][nt] = __builtin_amdgcn_mfma_f32_16x16x32_bf16(a1, bfr, uacc[1][nt], 0, 0, 0);
    }
  }
#pragma unroll
  for (int mt = 0; mt < 2; mt++)
#pragma unroll
    for (int nt = 0; nt < 4; nt++)
#pragma unroll
      for (int r = 0; r < 4; r++) {
        int row = mt * 16 + quad * 4 + r;
        if (row < 24) dst[row * 80 + nt * 16 + m16] = uacc[mt][nt][r];
      }

  if (LAST) {
    // attn mean over heads: 24 slots x 128 tokens from att LDS
    int c = threadIdx.x & 127;
    int half = threadIdx.x >> 7;
#pragma unroll
    for (int i0 = 0; i0 < 12; i0++) {
      int i = half * 12 + i0;
      float s = bf2f(__ushort_as_bfloat16(att[i * 136 + c]))
              + bf2f(__ushort_as_bfloat16(att[3264 + i * 136 + c]))
              + bf2f(__ushort_as_bfloat16(att[6528 + i * 136 + c]))
              + bf2f(__ushort_as_bfloat16(att[9792 + i * 136 + c]));
      size_t oidx = ((size_t)(b * 24 + i)) * 4096 + j0 + c;
      if (*flagp) ((bf16*)out)[196608 + oidx] = f2b(0.25f * s);
      else        ((float*)out)[196608 + oidx] = 0.25f * s;
    }
  }
}

// reduce 32 partials, divide by ws, pack to bf16 updB[b*24+i][h*64+d]
// grid (128 bh, 6 segs) = 768 blocks; p-loop fully unrolled -> 64 loads in flight.
__global__ __launch_bounds__(256) void upd_final_kernel(
    const float* __restrict__ pupd, bf16* __restrict__ updB)
{
  int bh = blockIdx.x; int b = bh >> 2, h = bh & 3;
  int idx = blockIdx.y * 256 + threadIdx.x;   // 0..1535
  int i = idx >> 6, d = idx & 63;
  const float* base = pupd + (size_t)bh * 32 * 1920 + i * 80;
  float v = 0.f, w = 0.f;
#pragma unroll
  for (int p = 0; p < 32; p++) {
    v += base[p * 1920 + d];
    w += base[p * 1920 + 64];
  }
  updB[((size_t)(b * 24 + i)) * 256 + h * 64 + d] = f2b(v / w);
}

__global__ __launch_bounds__(256) void gru_gate_kernel(
    const float* __restrict__ gi, const float* __restrict__ gh,
    float* __restrict__ sF, bf16* __restrict__ sB)
{
  int row = blockIdx.x, d = threadIdx.x;
  size_t o = (size_t)row * 768;
  float ir = gi[o + d], iz = gi[o + 256 + d], inn = gi[o + 512 + d];
  float hr = gh[o + d], hz = gh[o + 256 + d], hn = gh[o + 512 + d];
  float hv = sF[(size_t)row * 256 + d];
  float r = 1.f / (1.f + __expf(-(ir + hr)));
  float z = 1.f / (1.f + __expf(-(iz + hz)));
  float nn = tanhf(inn + r * hn);
  float sv = (1.f - z) * nn + z * hv;
  sF[(size_t)row * 256 + d] = sv;
  sB[(size_t)row * 256 + d] = f2b(sv);
}

__global__ __launch_bounds__(256) void out_slots_kernel(
    const float* __restrict__ sF, void* __restrict__ out, const int* flagp)
{
  int idx = blockIdx.x * 256 + threadIdx.x;  // 196608
  float v = sF[idx];
  if (*flagp) ((bf16*)out)[idx] = f2b(v);
  else        ((float*)out)[idx] = v;
}

// ---------------- workspace layout ----------------
static constexpr size_t SZ_BIG   = (size_t)32 * 4096 * 256 * 2;       // 67108864
static constexpr size_t OFF_BUF1 = 0;
static constexpr size_t OFF_BUF2 = OFF_BUF1 + SZ_BIG;
static constexpr size_t OFF_K    = OFF_BUF2 + SZ_BIG;
static constexpr size_t OFF_V    = OFF_K + SZ_BIG;                    // vT bf16 [256][131072]
static constexpr size_t OFF_Q    = OFF_V + SZ_BIG;                    // f32 [768][256]
static constexpr size_t OFF_QP   = OFF_Q + (size_t)768 * 256 * 4;
static constexpr size_t OFF_SNB  = OFF_QP + (size_t)32 * 4 * 32 * 64 * 2;
static constexpr size_t OFF_SF   = OFF_SNB + (size_t)768 * 256 * 2;
static constexpr size_t OFF_SB   = OFF_SF + (size_t)768 * 256 * 4;
static constexpr size_t OFF_UPD  = OFF_SB + (size_t)768 * 256 * 2;
static constexpr size_t OFF_GI   = OFF_UPD + (size_t)768 * 256 * 2;
static constexpr size_t OFF_GH   = OFF_GI + (size_t)768 * 768 * 4;
static constexpr size_t OFF_PUPD = OFF_GH + (size_t)768 * 768 * 4;    // 128*32*1920*4 = 31.5 MB
static constexpr size_t OFF_W1T  = OFF_PUPD + (size_t)128 * 32 * 1920 * 4;
static constexpr size_t OFF_W2T  = OFF_W1T + (size_t)256 * 256 * 2;
static constexpr size_t OFF_WQT  = OFF_W2T + (size_t)256 * 256 * 2;
static constexpr size_t OFF_WKT  = OFF_WQT + (size_t)256 * 256 * 2;
static constexpr size_t OFF_WVT  = OFF_WKT + (size_t)256 * 256 * 2;
static constexpr size_t OFF_GWIT = OFF_WVT + (size_t)256 * 256 * 2;
static constexpr size_t OFF_GWHT = OFF_GWIT + (size_t)256 * 768 * 2;
static constexpr size_t OFF_PAR  = OFF_GWHT + (size_t)256 * 768 * 2;  // 3584 f32
static constexpr size_t OFF_FLAG = OFF_PAR + (size_t)3584 * 4;
static constexpr size_t WS_NEED  = OFF_FLAG + 256;

extern "C" void kernel_launch(void* const* d_in, const int* in_sizes, int n_in,
                              void* d_out, int out_size, void* d_ws, size_t ws_size,
                              hipStream_t stream) {
  (void)in_sizes; (void)n_in; (void)out_size;
  if (ws_size < WS_NEED) return;

  const void* x         = d_in[0];
  const void* cond      = d_in[1];
  const void* pos_ln_g  = d_in[2];
  const void* pos_ln_b  = d_in[3];
  const void* pos_w1    = d_in[4];
  const void* pos_b1    = d_in[5];
  const void* pos_w2    = d_in[6];
  const void* pos_b2    = d_in[7];
  const void* in_ln_g   = d_in[8];
  const void* in_ln_b   = d_in[9];
  const void* slot_ln_g = d_in[10];
  const void* slot_ln_b = d_in[11];
  const void* Wq        = d_in[12];
  const void* Wk        = d_in[13];
  const void* Wv        = d_in[14];
  const void* gru_wi    = d_in[15];
  const void* gru_wh    = d_in[16];
  const void* gru_bi    = d_in[17];
  const void* gru_bh    = d_in[18];

  char* ws = (char*)d_ws;
  bf16*  buf1  = (bf16*)(ws + OFF_BUF1);
  bf16*  buf2  = (bf16*)(ws + OFF_BUF2);
  bf16*  kbuf  = (bf16*)(ws + OFF_K);
  bf16*  vT    = (bf16*)(ws + OFF_V);
  float* qbuf  = (float*)(ws + OFF_Q);
  bf16*  qp    = (bf16*)(ws + OFF_QP);
  bf16*  snb   = (bf16*)(ws + OFF_SNB);
  float* sF    = (float*)(ws + OFF_SF);
  bf16*  sB    = (bf16*)(ws + OFF_SB);
  bf16*  updB  = (bf16*)(ws + OFF_UPD);
  float* gi    = (float*)(ws + OFF_GI);
  float* gh    = (float*)(ws + OFF_GH);
  float* pupd  = (float*)(ws + OFF_PUPD);
  bf16*  w1t   = (bf16*)(ws + OFF_W1T);
  bf16*  w2t   = (bf16*)(ws + OFF_W2T);
  bf16*  wqt   = (bf16*)(ws + OFF_WQT);
  bf16*  wkt   = (bf16*)(ws + OFF_WKT);
  bf16*  wvt   = (bf16*)(ws + OFF_WVT);
  bf16*  gwit  = (bf16*)(ws + OFF_GWIT);
  bf16*  gwht  = (bf16*)(ws + OFF_GWHT);
  float* par   = (float*)(ws + OFF_PAR);
  int*   flagp = (int*)(ws + OFF_FLAG);

  // --- dtype detection + canonicalization ---
  detect_kernel<<<1, 1, 0, stream>>>((const unsigned short*)pos_ln_g, flagp);
  params_kernel<<<14, 256, 0, stream>>>(pos_ln_g, pos_ln_b, pos_b1, pos_b2,
                                        in_ln_g, in_ln_b, slot_ln_g, slot_ln_b,
                                        gru_bi, gru_bh, par, flagp);
  transpose_convert_kernel<<<256, 256, 0, stream>>>(pos_w1, w1t, 256, 256, flagp);
  transpose_convert_kernel<<<256, 256, 0, stream>>>(pos_w2, w2t, 256, 256, flagp);
  transpose_convert_kernel<<<256, 256, 0, stream>>>(Wq, wqt, 256, 256, flagp);
  transpose_convert_kernel<<<256, 256, 0, stream>>>(Wk, wkt, 256, 256, flagp);
  transpose_convert_kernel<<<256, 256, 0, stream>>>(Wv, wvt, 256, 256, flagp);
  transpose_convert_kernel<<<768, 256, 0, stream>>>(gru_wi, gwit, 256, 768, flagp);
  transpose_convert_kernel<<<768, 256, 0, stream>>>(gru_wh, gwht, 256, 768, flagp);
  init_slots_kernel<<<768, 256, 0, stream>>>(cond, sF, sB, flagp);

  // --- phase A: positional MLP + input LN + K/V projections ---
  ln_kernel<2><<<32768, 256, 0, stream>>>(x, par + 0, par + 256, buf1, 131072, flagp);
  gemm_kernel<true, true, true><<<dim3(2, 1024), 256, 0, stream>>>(
      buf1, w1t, par + 512, buf2, 131072, 256, 256);                   // h1 = relu(xln@w1+b1)
  gemm_kernel<true, false, true><<<dim3(2, 1024), 256, 0, stream>>>(
      buf2, w2t, par + 768, buf1, 131072, 256, 256);                   // feats = h1@w2+b2
  ln_kernel<0><<<32768, 256, 0, stream>>>(buf1, par + 1024, par + 1280, buf2, 131072, flagp);
  gemm_kernel<true, false, false><<<dim3(2, 1024), 256, 0, stream>>>(
      buf2, wkt, nullptr, kbuf, 131072, 256, 256);                     // k [token][d]
  gemm_kernel<true, false, false><<<dim3(1024, 2), 256, 0, stream>>>(
      wvt, buf2, nullptr, vT, 256, 131072, 256);                       // vT [d][token]

  // --- phase B: 3 slot-attention iterations ---
  for (int it = 0; it < 3; it++) {
    ln_kernel<1><<<192, 256, 0, stream>>>(sF, par + 1536, par + 1792, snb, 768, flagp);
    gemm_kernel<false, false, false><<<dim3(2, 6), 256, 0, stream>>>(
        snb, wqt, nullptr, qbuf, 768, 256, 256);                       // q (f32)
    repack_q_kernel<<<1024, 256, 0, stream>>>(qbuf, qp);
    if (it == 2)
      attn_iter_kernel<true><<<dim3(32, 32), 256, 0, stream>>>(qp, kbuf, vT, pupd, d_out, flagp);
    else
      attn_iter_kernel<false><<<dim3(32, 32), 256, 0, stream>>>(qp, kbuf, vT, pupd, d_out, flagp);
    upd_final_kernel<<<dim3(128, 6), 256, 0, stream>>>(pupd, updB);
    gemm_kernel<false, false, true><<<dim3(6, 6), 256, 0, stream>>>(
        updB, gwit, par + 2048, gi, 768, 768, 256);                    // gi
    gemm_kernel<false, false, true><<<dim3(6, 6), 256, 0, stream>>>(
        sB, gwht, par + 2816, gh, 768, 768, 256);                      // gh
    gru_gate_kernel<<<768, 256, 0, stream>>>(gi, gh, sF, sB);
  }

  // --- outputs ---
  out_slots_kernel<<<768, 256, 0, stream>>>(sF, d_out, flagp);
}